// Round 5
// baseline (225.921 us; speedup 1.0000x reference)
//
#include <hip/hip_runtime.h>

#define BATCH 8192
#define IN_F 4096
#define OUT_F 4096
#define RPB 8                    // rows per block
#define NBLK (BATCH / RPB)       // 1024 blocks = exactly 4/CU, co-resident

typedef float f4 __attribute__((ext_vector_type(4)));

// Producer/consumer wave specialization: waves 0-1 stream READS (row sums),
// waves 2-3 stream WRITES (scale+store). Chip-wide the read stream (the
// ~3.2 TB/s-capped side of this box) never drains while the write stream
// (6.7 TB/s-capable, posted) runs concurrently underneath — breaking the
// convoy effect that kept R3/R4 oscillating between read and write phases.
// Producer i feeds consumer i via LDS rs + acquire/release flag; producers
// never wait, so no deadlock regardless of scheduling.
__global__ __launch_bounds__(256) void
rank1_pc_kernel(const float* __restrict__ x, const float* __restrict__ w,
                float* __restrict__ out) {
    __shared__ float rs_sh[RPB];
    __shared__ int   flag[RPB];

    const int wave = threadIdx.x >> 6;
    const int lane = threadIdx.x & 63;
    const int row0 = blockIdx.x * RPB;

    if (threadIdx.x < RPB) flag[threadIdx.x] = 0;
    __syncthreads();          // only barrier in the kernel (flag init)

    if (wave < 2) {
        // ---------------- producer: continuous read stream ----------------
        for (int i = wave; i < RPB; i += 2) {
            const f4* x4 =
                reinterpret_cast<const f4*>(x + (size_t)(row0 + i) * IN_F);
            f4 v[16];                      // 64 VGPRs, static indices only
#pragma unroll
            for (int j = 0; j < 16; ++j)
                v[j] = __builtin_nontemporal_load(&x4[j * 64 + lane]);

            float s0 = 0.f, s1 = 0.f, s2 = 0.f, s3 = 0.f;
#pragma unroll
            for (int j = 0; j < 16; j += 4) {
                s0 += (v[j + 0].x + v[j + 0].y) + (v[j + 0].z + v[j + 0].w);
                s1 += (v[j + 1].x + v[j + 1].y) + (v[j + 1].z + v[j + 1].w);
                s2 += (v[j + 2].x + v[j + 2].y) + (v[j + 2].z + v[j + 2].w);
                s3 += (v[j + 3].x + v[j + 3].y) + (v[j + 3].z + v[j + 3].w);
            }
            float s = (s0 + s1) + (s2 + s3);
#pragma unroll
            for (int off = 1; off < 64; off <<= 1)
                s += __shfl_xor(s, off, 64);

            if (lane == 0) {
                rs_sh[i] = s;
                __hip_atomic_store(&flag[i], 1, __ATOMIC_RELEASE,
                                   __HIP_MEMORY_SCOPE_WORKGROUP);
            }
        }
    } else {
        // ---------------- consumer: continuous write stream ---------------
        const int c = wave - 2;                 // pairs with producer c
        const f4* w4 = reinterpret_cast<const f4*>(w);
        for (int i = c; i < RPB; i += 2) {
            while (__hip_atomic_load(&flag[i], __ATOMIC_ACQUIRE,
                                     __HIP_MEMORY_SCOPE_WORKGROUP) == 0)
                __builtin_amdgcn_s_sleep(1);
            const float s = rs_sh[i];

            f4* o4 = reinterpret_cast<f4*>(out + (size_t)(row0 + i) * OUT_F);
#pragma unroll
            for (int j = 0; j < 16; ++j) {
                f4 wv = w4[j * 64 + lane];      // L1-hot, 16 KiB shared
                f4 ov;
                ov.x = s * wv.x;
                ov.y = s * wv.y;
                ov.z = s * wv.z;
                ov.w = s * wv.w;
                __builtin_nontemporal_store(ov, &o4[j * 64 + lane]);
            }
        }
    }
}

extern "C" void kernel_launch(void* const* d_in, const int* in_sizes, int n_in,
                              void* d_out, int out_size, void* d_ws, size_t ws_size,
                              hipStream_t stream) {
    const float* x = (const float*)d_in[0];   // [8192, 4096] fp32
    const float* w = (const float*)d_in[1];   // [1, 4096] fp32
    float* out = (float*)d_out;               // [8192, 4096] fp32
    rank1_pc_kernel<<<NBLK, 256, 0, stream>>>(x, w, out);
}

// Round 6
// 219.061 us; speedup vs baseline: 1.0313x; 1.0313x over previous
//
#include <hip/hip_runtime.h>

#define BATCH 8192
#define IN_F 4096
#define OUT_F 4096

typedef float f4 __attribute__((ext_vector_type(4)));

// ---------------- Kernel 1: row sums, one wave (64 lanes) per row ----------
// Pure read stream at the ~3.2 TB/s read-path cap. NT loads: x is read once,
// L3 is full of poison-fill data — bypass allocation (R1->R2: +13 us).
// Low VGPR (~24) -> full 8 waves/SIMD occupancy.
__global__ __launch_bounds__(256) void
rowsum_kernel(const float* __restrict__ x, float* __restrict__ rs) {
    const int wave = threadIdx.x >> 6;
    const int lane = threadIdx.x & 63;
    const int row  = (blockIdx.x << 2) + wave;

    const f4* x4 = reinterpret_cast<const f4*>(x + (size_t)row * IN_F);

    // 4096 floats = 1024 f4; 64 lanes x 16 f4, each j covers contiguous 1 KiB.
    float s0 = 0.f, s1 = 0.f, s2 = 0.f, s3 = 0.f;
#pragma unroll
    for (int j = 0; j < 16; j += 4) {
        f4 a = __builtin_nontemporal_load(&x4[(j + 0) * 64 + lane]);
        f4 b = __builtin_nontemporal_load(&x4[(j + 1) * 64 + lane]);
        f4 c = __builtin_nontemporal_load(&x4[(j + 2) * 64 + lane]);
        f4 d = __builtin_nontemporal_load(&x4[(j + 3) * 64 + lane]);
        s0 += (a.x + a.y) + (a.z + a.w);
        s1 += (b.x + b.y) + (b.z + b.w);
        s2 += (c.x + c.y) + (c.z + c.w);
        s3 += (d.x + d.y) + (d.z + d.w);
    }
    float s = (s0 + s1) + (s2 + s3);

#pragma unroll
    for (int off = 32; off > 0; off >>= 1)
        s += __shfl_down(s, off, 64);

    if (lane == 0) rs[row] = s;
}

// ---------------- Kernel 2: out[row,:] = rs[row] * w[:] --------------------
// Pure write stream. CHANGE vs R2: REGULAR stores (not nontemporal).
// The 6.7 TB/s write evidence (fillBufferAligned) is the L2-mediated store
// path; NT write-through was never isolated and may be the slower path.
// This kernel reads only ~48 KB (w + rs), so L2/L3 pollution costs nothing.
__global__ __launch_bounds__(256) void
scale_kernel(const float* __restrict__ rs, const float* __restrict__ w,
             float* __restrict__ out) {
    const int row = blockIdx.x;
    const int tid = threadIdx.x;

    const float r = rs[row];

    const f4* w4 = reinterpret_cast<const f4*>(w);
    f4* o4 = reinterpret_cast<f4*>(out + (size_t)row * OUT_F);

#pragma unroll
    for (int j = 0; j < 4; ++j) {
        f4 wv = w4[j * 256 + tid];
        f4 ov;
        ov.x = r * wv.x;
        ov.y = r * wv.y;
        ov.z = r * wv.z;
        ov.w = r * wv.w;
        o4[j * 256 + tid] = ov;
    }
}

extern "C" void kernel_launch(void* const* d_in, const int* in_sizes, int n_in,
                              void* d_out, int out_size, void* d_ws, size_t ws_size,
                              hipStream_t stream) {
    const float* x = (const float*)d_in[0];   // [8192, 4096] fp32
    const float* w = (const float*)d_in[1];   // [1, 4096] fp32
    float* out = (float*)d_out;               // [8192, 4096] fp32
    float* rs = (float*)d_ws;                 // 8192 floats = 32 KiB workspace

    rowsum_kernel<<<BATCH / 4, 256, 0, stream>>>(x, rs);
    scale_kernel<<<BATCH, 256, 0, stream>>>(rs, w, out);
}